// Round 1
// baseline (80.355 us; speedup 1.0000x reference)
//
#include <hip/hip_runtime.h>

#define TOPK_K 13
#define KPAD 16

// ---- shared math helpers: MUST be used identically by k1 and k2 so that
// align-metric values are bit-identical across passes (threshold equality). ----

__device__ __forceinline__ float iou_clip(const float4 g, const float4 p) {
    float ix1 = fmaxf(g.x, p.x), iy1 = fmaxf(g.y, p.y);
    float ix2 = fminf(g.z, p.z), iy2 = fminf(g.w, p.w);
    float iw = fmaxf(ix2 - ix1, 0.f);
    float ih = fmaxf(iy2 - iy1, 0.f);
    float inter = iw * ih;
    float a1 = (g.z - g.x) * (g.w - g.y);
    float a2 = (p.z - p.x) * (p.w - p.y);
    float iou = inter / (a1 + a2 - inter + 1e-7f);
    return fmaxf(iou, 0.f);
}

__device__ __forceinline__ float in_box(float ax, float ay, const float4 g) {
    float m = fminf(fminf(ax - g.x, ay - g.y), fminf(g.z - ax, g.w - ay));
    return (m > 0.f) ? 1.f : 0.f;
}

__device__ __forceinline__ float align_metric_f(float sqs, float iou, float valid) {
    float p2 = iou * iou;
    float p6 = p2 * p2 * p2;
    return sqs * p6 * valid;
}

// ---- Kernel 1: per-(b,g) top-13 threshold over NA anchors. One wave per (b,g). ----
__global__ __launch_bounds__(256) void k_thresh(
    const float* __restrict__ pd_scores, const float* __restrict__ pd_bboxes,
    const float* __restrict__ anc, const float* __restrict__ gt_bboxes,
    const float* __restrict__ mask_gt, float* __restrict__ thr,
    int B, int G, int NA)
{
    int w = blockIdx.x * (blockDim.x >> 6) + (threadIdx.x >> 6);
    int lane = threadIdx.x & 63;
    if (w >= B * G) return;
    int b = w / G;

    float4 gb = *(const float4*)(gt_bboxes + (size_t)w * 4);
    float mg = mask_gt[w];
    if (mg == 0.f) { if (lane == 0) thr[w] = 0.f; return; }

    const float* ps = pd_scores + (size_t)b * NA;
    const float* pb = pd_bboxes + (size_t)b * NA * 4;

    // per-lane top-KPAD, descending, register-resident (all indices static)
    float t[KPAD];
    #pragma unroll
    for (int i = 0; i < KPAD; ++i) t[i] = 0.f;

    for (int a = lane; a < NA; a += 64) {
        float ax = anc[2 * a], ay = anc[2 * a + 1];
        float v = in_box(ax, ay, gb);
        if (v != 0.f) {
            float4 p = *(const float4*)(pb + (size_t)a * 4);
            float iou = iou_clip(gb, p);
            float sqs = sqrtf(fmaxf(ps[a], 0.f));
            float am = align_metric_f(sqs, iou, v * mg);
            if (am > t[KPAD - 1]) {
                t[KPAD - 1] = am;
                #pragma unroll
                for (int i = KPAD - 1; i > 0; --i) {
                    float hi = fmaxf(t[i - 1], t[i]);
                    float lo = fminf(t[i - 1], t[i]);
                    t[i - 1] = hi; t[i] = lo;
                }
            }
        }
    }

    // butterfly merge across 64 lanes: merge two sorted-desc KPAD lists, keep top KPAD
    for (int off = 1; off < 64; off <<= 1) {
        float o[KPAD], m[KPAD];
        #pragma unroll
        for (int i = 0; i < KPAD; ++i) o[i] = __shfl_xor(t[i], off, 64);
        #pragma unroll
        for (int i = 0; i < KPAD; ++i) m[i] = fmaxf(t[i], o[KPAD - 1 - i]);
        // m is bitonic; sort descending with static bitonic-merge network
        #pragma unroll
        for (int s = 8; s >= 1; s >>= 1) {
            #pragma unroll
            for (int i = 0; i < KPAD; ++i) {
                if ((i & s) == 0) {
                    float hi = fmaxf(m[i], m[i + s]);
                    float lo = fminf(m[i], m[i + s]);
                    m[i] = hi; m[i + s] = lo;
                }
            }
        }
        #pragma unroll
        for (int i = 0; i < KPAD; ++i) t[i] = m[i];
    }

    if (lane == 0) thr[w] = t[TOPK_K - 1];
}

// ---- Kernel 2: per-(b,anchor) assignment. ----
__global__ __launch_bounds__(256) void k_assign(
    const float* __restrict__ pd_scores, const float* __restrict__ pd_bboxes,
    const float* __restrict__ anc, const int* __restrict__ gt_labels,
    const float* __restrict__ gt_bboxes, const float* __restrict__ mask_gt,
    const float* __restrict__ thr,
    float* __restrict__ out_labels, float* __restrict__ out_bboxes,
    float* __restrict__ out_fg,
    int* __restrict__ ws_tgt, float* __restrict__ ws_amv,
    int* __restrict__ pam, int* __restrict__ pim,
    int B, int G, int NA)
{
    __shared__ float4 sbox[128];
    __shared__ float sthr[128];
    __shared__ float smask[128];

    int b = blockIdx.y;
    int tid = threadIdx.x;
    int a = blockIdx.x * blockDim.x + tid;

    if (tid < G) {
        sbox[tid]  = *(const float4*)(gt_bboxes + ((size_t)b * G + tid) * 4);
        sthr[tid]  = thr[b * G + tid];
        smask[tid] = mask_gt[b * G + tid];
    }
    __syncthreads();
    if (a >= NA) return;

    float ax = anc[2 * a], ay = anc[2 * a + 1];
    float4 p = *(const float4*)(pd_bboxes + ((size_t)b * NA + a) * 4);
    float sqs = sqrtf(fmaxf(pd_scores[(size_t)b * NA + a], 0.f));

    int fg = 0, first = -1, bestg = 0;
    float bestiou = -1.f;
    for (int g = 0; g < G; ++g) {
        float4 gbb = sbox[g];
        float v = in_box(ax, ay, gbb) * smask[g];
        float iou = iou_clip(gbb, p);
        float am = align_metric_f(sqs, iou, v);
        bool mp = (am >= sthr[g]) && (v != 0.f);
        fg += mp ? 1 : 0;
        if (mp && first < 0) first = g;
        if (iou > bestiou) { bestiou = iou; bestg = g; }  // strict > = first occurrence (jnp.argmax)
    }

    int tgt; float fgm;
    if (fg > 1) { tgt = bestg; fgm = 1.f; }          // disputed: one-hot of best IoU over ALL g
    else        { tgt = (first >= 0) ? first : 0; fgm = (float)fg; }

    // recompute am/iou at the target gt (identical code path -> identical bits)
    float4 gbt = sbox[tgt];
    float vt = in_box(ax, ay, gbt) * smask[tgt];
    float iout = iou_clip(gbt, p);
    float amt = align_metric_f(sqs, iout, vt);
    float amv = (fgm != 0.f) ? amt : 0.f;
    float iov = (fgm != 0.f) ? iout : 0.f;

    size_t o = (size_t)b * NA + a;
    int lbl = gt_labels[(size_t)b * G + tgt];
    if (lbl < 0) lbl = 0;
    out_labels[o] = (float)lbl;
    *(float4*)(out_bboxes + o * 4) = gbt;
    out_fg[o] = fgm;
    ws_tgt[o] = tgt;
    ws_amv[o] = amv;

    if (fgm != 0.f) {
        int gi = b * G + tgt;
        atomicMax(&pam[gi], __float_as_int(amv));  // values >= 0: int-bit compare == float compare
        atomicMax(&pim[gi], __float_as_int(iov));
    }
}

// ---- Kernel 3: normalized target scores. ----
__global__ __launch_bounds__(256) void k_scores(
    const int* __restrict__ ws_tgt, const float* __restrict__ ws_amv,
    const int* __restrict__ pam, const int* __restrict__ pim,
    const float* __restrict__ out_labels,
    float* __restrict__ out_scores,
    int B, int G, int NA)
{
    int i = blockIdx.x * blockDim.x + threadIdx.x;
    if (i >= B * NA) return;
    int b = i / NA;
    int tgt = ws_tgt[i];
    float amv = ws_amv[i];
    float pa = __int_as_float(pam[b * G + tgt]);
    float pi = __int_as_float(pim[b * G + tgt]);
    float wgt = amv / (pa + 1e-9f) * pi;   // (am / (pos_align_max+EPS)) * pos_iou_max
    float onehot = (out_labels[i] == 0.f) ? 1.f : 0.f;  // NC==1
    out_scores[i] = onehot * wgt;
}

extern "C" void kernel_launch(void* const* d_in, const int* in_sizes, int n_in,
                              void* d_out, int out_size, void* d_ws, size_t ws_size,
                              hipStream_t stream) {
    const float* pd_scores = (const float*)d_in[0];
    const float* pd_bboxes = (const float*)d_in[1];
    const float* anc       = (const float*)d_in[2];
    const int*   gt_labels = (const int*)d_in[3];
    const float* gt_bboxes = (const float*)d_in[4];
    const float* mask_gt   = (const float*)d_in[5];

    int NA = in_sizes[2] / 2;
    int B  = in_sizes[0] / NA;
    int G  = in_sizes[4] / (B * 4);

    float* out = (float*)d_out;
    float* out_labels = out;                               // (B,NA)
    float* out_bboxes = out_labels + (size_t)B * NA;       // (B,NA,4)
    float* out_scores = out_bboxes + (size_t)B * NA * 4;   // (B,NA,1)
    float* out_fg     = out_scores + (size_t)B * NA;       // (B,NA)

    int BG = B * G;
    float* thr    = (float*)d_ws;                 // BG
    int*   pam    = (int*)(thr + BG);             // BG
    int*   pim    = pam + BG;                     // BG
    int*   ws_tgt = pim + BG;                     // B*NA
    float* ws_amv = (float*)(ws_tgt + (size_t)B * NA);  // B*NA

    // zero the atomic-max accumulators (ws is poisoned 0xAA, not re-poisoned between replays)
    hipMemsetAsync(pam, 0, sizeof(int) * (size_t)BG * 2, stream);

    k_thresh<<<dim3((BG + 3) / 4), dim3(256), 0, stream>>>(
        pd_scores, pd_bboxes, anc, gt_bboxes, mask_gt, thr, B, G, NA);

    k_assign<<<dim3((NA + 255) / 256, B), dim3(256), 0, stream>>>(
        pd_scores, pd_bboxes, anc, gt_labels, gt_bboxes, mask_gt, thr,
        out_labels, out_bboxes, out_fg, ws_tgt, ws_amv, pam, pim, B, G, NA);

    k_scores<<<dim3((B * NA + 255) / 256), dim3(256), 0, stream>>>(
        ws_tgt, ws_amv, pam, pim, out_labels, out_scores, B, G, NA);
}

// Round 2
// 58.541 us; speedup vs baseline: 1.3726x; 1.3726x over previous
//
#include <hip/hip_runtime.h>

#define TOPK_K 13
#define KPAD 16

// ---- shared math helpers: MUST be used identically by k1 and k2 so that
// align-metric values are bit-identical across passes (threshold equality). ----

__device__ __forceinline__ float iou_clip(const float4 g, const float4 p) {
    float ix1 = fmaxf(g.x, p.x), iy1 = fmaxf(g.y, p.y);
    float ix2 = fminf(g.z, p.z), iy2 = fminf(g.w, p.w);
    float iw = fmaxf(ix2 - ix1, 0.f);
    float ih = fmaxf(iy2 - iy1, 0.f);
    float inter = iw * ih;
    float a1 = (g.z - g.x) * (g.w - g.y);
    float a2 = (p.z - p.x) * (p.w - p.y);
    float iou = inter / (a1 + a2 - inter + 1e-7f);
    return fmaxf(iou, 0.f);
}

__device__ __forceinline__ float in_box(float ax, float ay, const float4 g) {
    float m = fminf(fminf(ax - g.x, ay - g.y), fminf(g.z - ax, g.w - ay));
    return (m > 0.f) ? 1.f : 0.f;
}

__device__ __forceinline__ float align_metric_f(float sqs, float iou, float valid) {
    float p2 = iou * iou;
    float p6 = p2 * p2 * p2;
    return sqs * p6 * valid;
}

// ---- Kernel 1: per-(b,g) top-13 threshold. One wave per (b,g).
// Anchors form a regular grid per stride level, so the in-box candidates are a
// small analytic rectangle per level (~50-300 anchors, not 8400). Enumerate the
// rectangle (+1 margin) and re-apply the exact in_box test bit-identically. ----
__global__ __launch_bounds__(256) void k_thresh(
    const float* __restrict__ pd_scores, const float* __restrict__ pd_bboxes,
    const float* __restrict__ gt_bboxes,
    const float* __restrict__ mask_gt, float* __restrict__ thr,
    int B, int G, int NA)
{
    int w = blockIdx.x * (blockDim.x >> 6) + (threadIdx.x >> 6);
    int lane = threadIdx.x & 63;
    if (w >= B * G) return;
    int b = w / G;

    float4 gb = *(const float4*)(gt_bboxes + (size_t)w * 4);
    float mg = mask_gt[w];
    if (mg == 0.f) { if (lane == 0) thr[w] = 0.f; return; }

    const float* ps = pd_scores + (size_t)b * NA;
    const float* pb = pd_bboxes + (size_t)b * NA * 4;

    // per-lane top-KPAD, descending, register-resident (all indices static)
    float t[KPAD];
    #pragma unroll
    for (int i = 0; i < KPAD; ++i) t[i] = 0.f;

    #pragma unroll
    for (int lvl = 0; lvl < 3; ++lvl) {
        const int s   = 8 << lvl;                      // 8,16,32
        const int n   = (lvl == 0) ? 80 : (lvl == 1 ? 40 : 20);
        const int off = (lvl == 0) ? 0  : (lvl == 1 ? 6400 : 8000);
        const float sf = (float)s;
        // conservative index rectangle (in_box filters exactly afterwards)
        int ix0 = max(0,     (int)floorf(gb.x / sf - 0.5f));
        int iy0 = max(0,     (int)floorf(gb.y / sf - 0.5f));
        int ix1 = min(n - 1, (int)ceilf (gb.z / sf - 0.5f));
        int iy1 = min(n - 1, (int)ceilf (gb.w / sf - 0.5f));
        int wdt = ix1 - ix0 + 1, hgt = iy1 - iy0 + 1;
        if (wdt <= 0 || hgt <= 0) continue;
        int cnt = wdt * hgt;
        for (int c = lane; c < cnt; c += 64) {
            int ix = ix0 + (c % wdt);
            int iy = iy0 + (c / wdt);
            float ax = (ix + 0.5f) * sf;   // exact f32, bit-identical to reference anc
            float ay = (iy + 0.5f) * sf;
            float v = in_box(ax, ay, gb);
            if (v != 0.f) {
                int a = off + iy * n + ix;
                float4 p = *(const float4*)(pb + (size_t)a * 4);
                float iou = iou_clip(gb, p);
                float sqs = sqrtf(fmaxf(ps[a], 0.f));
                float am = align_metric_f(sqs, iou, v * mg);
                if (am > t[KPAD - 1]) {
                    t[KPAD - 1] = am;
                    #pragma unroll
                    for (int i = KPAD - 1; i > 0; --i) {
                        float hi = fmaxf(t[i - 1], t[i]);
                        float lo = fminf(t[i - 1], t[i]);
                        t[i - 1] = hi; t[i] = lo;
                    }
                }
            }
        }
    }

    // butterfly merge across 64 lanes: merge two sorted-desc KPAD lists, keep top KPAD
    for (int off = 1; off < 64; off <<= 1) {
        float o[KPAD], m[KPAD];
        #pragma unroll
        for (int i = 0; i < KPAD; ++i) o[i] = __shfl_xor(t[i], off, 64);
        #pragma unroll
        for (int i = 0; i < KPAD; ++i) m[i] = fmaxf(t[i], o[KPAD - 1 - i]);
        // m is bitonic; sort descending with static bitonic-merge network
        #pragma unroll
        for (int s = 8; s >= 1; s >>= 1) {
            #pragma unroll
            for (int i = 0; i < KPAD; ++i) {
                if ((i & s) == 0) {
                    float hi = fmaxf(m[i], m[i + s]);
                    float lo = fminf(m[i], m[i + s]);
                    m[i] = hi; m[i + s] = lo;
                }
            }
        }
        #pragma unroll
        for (int i = 0; i < KPAD; ++i) t[i] = m[i];
    }

    if (lane == 0) thr[w] = t[TOPK_K - 1];
}

// ---- Kernel 2: per-(b,anchor) assignment. ----
__global__ __launch_bounds__(256) void k_assign(
    const float* __restrict__ pd_scores, const float* __restrict__ pd_bboxes,
    const float* __restrict__ anc, const int* __restrict__ gt_labels,
    const float* __restrict__ gt_bboxes, const float* __restrict__ mask_gt,
    const float* __restrict__ thr,
    float* __restrict__ out_labels, float* __restrict__ out_bboxes,
    float* __restrict__ out_fg,
    int* __restrict__ ws_tgt, float* __restrict__ ws_amv,
    int* __restrict__ pam, int* __restrict__ pim,
    int B, int G, int NA)
{
    __shared__ float4 sbox[128];
    __shared__ float sthr[128];
    __shared__ float smask[128];

    int b = blockIdx.y;
    int tid = threadIdx.x;
    int a = blockIdx.x * blockDim.x + tid;

    if (tid < G) {
        sbox[tid]  = *(const float4*)(gt_bboxes + ((size_t)b * G + tid) * 4);
        sthr[tid]  = thr[b * G + tid];
        smask[tid] = mask_gt[b * G + tid];
    }
    __syncthreads();
    if (a >= NA) return;

    float ax = anc[2 * a], ay = anc[2 * a + 1];
    float4 p = *(const float4*)(pd_bboxes + ((size_t)b * NA + a) * 4);
    float sqs = sqrtf(fmaxf(pd_scores[(size_t)b * NA + a], 0.f));

    int fg = 0, first = -1, bestg = 0;
    float bestiou = -1.f;
    for (int g = 0; g < G; ++g) {
        float4 gbb = sbox[g];
        float v = in_box(ax, ay, gbb) * smask[g];
        float iou = iou_clip(gbb, p);
        float am = align_metric_f(sqs, iou, v);
        bool mp = (am >= sthr[g]) && (v != 0.f);
        fg += mp ? 1 : 0;
        if (mp && first < 0) first = g;
        if (iou > bestiou) { bestiou = iou; bestg = g; }  // strict > = first occurrence (jnp.argmax)
    }

    int tgt; float fgm;
    if (fg > 1) { tgt = bestg; fgm = 1.f; }          // disputed: one-hot of best IoU over ALL g
    else        { tgt = (first >= 0) ? first : 0; fgm = (float)fg; }

    // recompute am/iou at the target gt (identical code path -> identical bits)
    float4 gbt = sbox[tgt];
    float vt = in_box(ax, ay, gbt) * smask[tgt];
    float iout = iou_clip(gbt, p);
    float amt = align_metric_f(sqs, iout, vt);
    float amv = (fgm != 0.f) ? amt : 0.f;
    float iov = (fgm != 0.f) ? iout : 0.f;

    size_t o = (size_t)b * NA + a;
    int lbl = gt_labels[(size_t)b * G + tgt];
    if (lbl < 0) lbl = 0;
    out_labels[o] = (float)lbl;
    *(float4*)(out_bboxes + o * 4) = gbt;
    out_fg[o] = fgm;
    ws_tgt[o] = tgt;
    ws_amv[o] = amv;

    if (fgm != 0.f) {
        int gi = b * G + tgt;
        atomicMax(&pam[gi], __float_as_int(amv));  // values >= 0: int-bit compare == float compare
        atomicMax(&pim[gi], __float_as_int(iov));
    }
}

// ---- Kernel 3: normalized target scores. ----
__global__ __launch_bounds__(256) void k_scores(
    const int* __restrict__ ws_tgt, const float* __restrict__ ws_amv,
    const int* __restrict__ pam, const int* __restrict__ pim,
    const float* __restrict__ out_labels,
    float* __restrict__ out_scores,
    int B, int G, int NA)
{
    int i = blockIdx.x * blockDim.x + threadIdx.x;
    if (i >= B * NA) return;
    int b = i / NA;
    int tgt = ws_tgt[i];
    float amv = ws_amv[i];
    float pa = __int_as_float(pam[b * G + tgt]);
    float pi = __int_as_float(pim[b * G + tgt]);
    float wgt = amv / (pa + 1e-9f) * pi;   // (am / (pos_align_max+EPS)) * pos_iou_max
    float onehot = (out_labels[i] == 0.f) ? 1.f : 0.f;  // NC==1
    out_scores[i] = onehot * wgt;
}

extern "C" void kernel_launch(void* const* d_in, const int* in_sizes, int n_in,
                              void* d_out, int out_size, void* d_ws, size_t ws_size,
                              hipStream_t stream) {
    const float* pd_scores = (const float*)d_in[0];
    const float* pd_bboxes = (const float*)d_in[1];
    const float* anc       = (const float*)d_in[2];
    const int*   gt_labels = (const int*)d_in[3];
    const float* gt_bboxes = (const float*)d_in[4];
    const float* mask_gt   = (const float*)d_in[5];

    int NA = in_sizes[2] / 2;
    int B  = in_sizes[0] / NA;
    int G  = in_sizes[4] / (B * 4);

    float* out = (float*)d_out;
    float* out_labels = out;                               // (B,NA)
    float* out_bboxes = out_labels + (size_t)B * NA;       // (B,NA,4)
    float* out_scores = out_bboxes + (size_t)B * NA * 4;   // (B,NA,1)
    float* out_fg     = out_scores + (size_t)B * NA;       // (B,NA)

    int BG = B * G;
    float* thr    = (float*)d_ws;                 // BG
    int*   pam    = (int*)(thr + BG);             // BG
    int*   pim    = pam + BG;                     // BG
    int*   ws_tgt = pim + BG;                     // B*NA
    float* ws_amv = (float*)(ws_tgt + (size_t)B * NA);  // B*NA

    // zero the atomic-max accumulators (ws is poisoned 0xAA, not re-poisoned between replays)
    hipMemsetAsync(pam, 0, sizeof(int) * (size_t)BG * 2, stream);

    k_thresh<<<dim3((BG + 3) / 4), dim3(256), 0, stream>>>(
        pd_scores, pd_bboxes, gt_bboxes, mask_gt, thr, B, G, NA);

    k_assign<<<dim3((NA + 255) / 256, B), dim3(256), 0, stream>>>(
        pd_scores, pd_bboxes, anc, gt_labels, gt_bboxes, mask_gt, thr,
        out_labels, out_bboxes, out_fg, ws_tgt, ws_amv, pam, pim, B, G, NA);

    k_scores<<<dim3((B * NA + 255) / 256), dim3(256), 0, stream>>>(
        ws_tgt, ws_amv, pam, pim, out_labels, out_scores, B, G, NA);
}

// Round 3
// 46.202 us; speedup vs baseline: 1.7392x; 1.2671x over previous
//
#include <hip/hip_runtime.h>

#define TOPK_K 13
#define KPAD 16

// ---- shared math helpers: used identically by k_gt (threshold+scatter) and
// k_anchor (recompute at target) so am values are bit-identical everywhere. ----

__device__ __forceinline__ float iou_clip(const float4 g, const float4 p) {
    float ix1 = fmaxf(g.x, p.x), iy1 = fmaxf(g.y, p.y);
    float ix2 = fminf(g.z, p.z), iy2 = fminf(g.w, p.w);
    float iw = fmaxf(ix2 - ix1, 0.f);
    float ih = fmaxf(iy2 - iy1, 0.f);
    float inter = iw * ih;
    float a1 = (g.z - g.x) * (g.w - g.y);
    float a2 = (p.z - p.x) * (p.w - p.y);
    float iou = inter / (a1 + a2 - inter + 1e-7f);
    return fmaxf(iou, 0.f);
}

__device__ __forceinline__ float in_box(float ax, float ay, const float4 g) {
    float m = fminf(fminf(ax - g.x, ay - g.y), fminf(g.z - ax, g.w - ay));
    return (m > 0.f) ? 1.f : 0.f;
}

__device__ __forceinline__ float align_metric_f(float sqs, float iou, float valid) {
    float p2 = iou * iou;
    float p6 = p2 * p2 * p2;
    return sqs * p6 * valid;
}

// ---- Kernel 0: init atomic state (ws poisoned 0xAA; not re-poisoned between replays) ----
__global__ __launch_bounds__(256) void k_init(
    int* __restrict__ cnt, int* __restrict__ ming,
    int* __restrict__ pam, int* __restrict__ pim, int BNA, int BG)
{
    int i = blockIdx.x * blockDim.x + threadIdx.x;
    if (i < BNA) { cnt[i] = 0; ming[i] = 64; }
    if (i < BG)  { pam[i] = 0; pim[i] = 0; }
}

// ---- Kernel 1: per-(b,g) wave. Pass 1: top-13 threshold over the analytic
// anchor rectangle. Pass 2: scatter passing anchors (am >= thr, in-box) into
// per-anchor (count, min-g) via atomics. <= ~13 positives per gt. ----
__global__ __launch_bounds__(256) void k_gt(
    const float* __restrict__ pd_scores, const float* __restrict__ pd_bboxes,
    const float* __restrict__ gt_bboxes, const float* __restrict__ mask_gt,
    int* __restrict__ cnt, int* __restrict__ ming,
    int B, int G, int NA)
{
    int w = blockIdx.x * (blockDim.x >> 6) + (threadIdx.x >> 6);
    int lane = threadIdx.x & 63;
    if (w >= B * G) return;
    int b = w / G;
    int g = w - b * G;

    if (mask_gt[w] == 0.f) return;
    float4 gb = *(const float4*)(gt_bboxes + (size_t)w * 4);

    const float* ps = pd_scores + (size_t)b * NA;
    const float* pb = pd_bboxes + (size_t)b * NA * 4;

    // rectangle bounds per level (conservative; exact in_box filter follows)
    int rix0[3], riy0[3], rix1[3], riy1[3];
    #pragma unroll
    for (int lvl = 0; lvl < 3; ++lvl) {
        const int n = (lvl == 0) ? 80 : (lvl == 1 ? 40 : 20);
        const float sf = (float)(8 << lvl);
        rix0[lvl] = max(0,     (int)floorf(gb.x / sf - 0.5f));
        riy0[lvl] = max(0,     (int)floorf(gb.y / sf - 0.5f));
        rix1[lvl] = min(n - 1, (int)ceilf (gb.z / sf - 0.5f));
        riy1[lvl] = min(n - 1, (int)ceilf (gb.w / sf - 0.5f));
    }

    // ---- pass 1: per-lane top-KPAD (descending, static indices) ----
    float t[KPAD];
    #pragma unroll
    for (int i = 0; i < KPAD; ++i) t[i] = 0.f;

    #pragma unroll
    for (int lvl = 0; lvl < 3; ++lvl) {
        const int n   = (lvl == 0) ? 80 : (lvl == 1 ? 40 : 20);
        const int off = (lvl == 0) ? 0  : (lvl == 1 ? 6400 : 8000);
        const float sf = (float)(8 << lvl);
        int wdt = rix1[lvl] - rix0[lvl] + 1, hgt = riy1[lvl] - riy0[lvl] + 1;
        if (wdt <= 0 || hgt <= 0) continue;
        int n_c = wdt * hgt;
        for (int c = lane; c < n_c; c += 64) {
            int ix = rix0[lvl] + (c % wdt);
            int iy = riy0[lvl] + (c / wdt);
            float ax = (ix + 0.5f) * sf;   // exact f32, bit-identical to reference anc
            float ay = (iy + 0.5f) * sf;
            if (in_box(ax, ay, gb) != 0.f) {
                int a = off + iy * n + ix;
                float4 p = *(const float4*)(pb + (size_t)a * 4);
                float iou = iou_clip(gb, p);
                float sqs = sqrtf(fmaxf(ps[a], 0.f));
                float am = align_metric_f(sqs, iou, 1.f);
                if (am > t[KPAD - 1]) {
                    t[KPAD - 1] = am;
                    #pragma unroll
                    for (int i = KPAD - 1; i > 0; --i) {
                        float hi = fmaxf(t[i - 1], t[i]);
                        float lo = fminf(t[i - 1], t[i]);
                        t[i - 1] = hi; t[i] = lo;
                    }
                }
            }
        }
    }

    // butterfly all-reduce merge: every lane ends with the global top-KPAD
    for (int off = 1; off < 64; off <<= 1) {
        float o[KPAD], m[KPAD];
        #pragma unroll
        for (int i = 0; i < KPAD; ++i) o[i] = __shfl_xor(t[i], off, 64);
        #pragma unroll
        for (int i = 0; i < KPAD; ++i) m[i] = fmaxf(t[i], o[KPAD - 1 - i]);
        #pragma unroll
        for (int s = 8; s >= 1; s >>= 1) {
            #pragma unroll
            for (int i = 0; i < KPAD; ++i) {
                if ((i & s) == 0) {
                    float hi = fmaxf(m[i], m[i + s]);
                    float lo = fminf(m[i], m[i + s]);
                    m[i] = hi; m[i + s] = lo;
                }
            }
        }
        #pragma unroll
        for (int i = 0; i < KPAD; ++i) t[i] = m[i];
    }
    float thr = t[TOPK_K - 1];

    // ---- pass 2: scatter passing anchors ----
    int* cntb  = cnt  + (size_t)b * NA;
    int* mingb = ming + (size_t)b * NA;
    #pragma unroll
    for (int lvl = 0; lvl < 3; ++lvl) {
        const int n   = (lvl == 0) ? 80 : (lvl == 1 ? 40 : 20);
        const int off = (lvl == 0) ? 0  : (lvl == 1 ? 6400 : 8000);
        const float sf = (float)(8 << lvl);
        int wdt = rix1[lvl] - rix0[lvl] + 1, hgt = riy1[lvl] - riy0[lvl] + 1;
        if (wdt <= 0 || hgt <= 0) continue;
        int n_c = wdt * hgt;
        for (int c = lane; c < n_c; c += 64) {
            int ix = rix0[lvl] + (c % wdt);
            int iy = riy0[lvl] + (c / wdt);
            float ax = (ix + 0.5f) * sf;
            float ay = (iy + 0.5f) * sf;
            if (in_box(ax, ay, gb) != 0.f) {
                int a = off + iy * n + ix;
                float4 p = *(const float4*)(pb + (size_t)a * 4);
                float iou = iou_clip(gb, p);
                float sqs = sqrtf(fmaxf(ps[a], 0.f));
                float am = align_metric_f(sqs, iou, 1.f);
                if (am >= thr) {
                    atomicAdd(&cntb[a], 1);
                    atomicMin(&mingb[a], g);
                }
            }
        }
    }
}

// ---- Kernel 2: per-(b,anchor) resolve + outputs. ----
__global__ __launch_bounds__(256) void k_anchor(
    const float* __restrict__ pd_scores, const float* __restrict__ pd_bboxes,
    const float* __restrict__ anc, const int* __restrict__ gt_labels,
    const float* __restrict__ gt_bboxes, const float* __restrict__ mask_gt,
    const int* __restrict__ cnt_arr, const int* __restrict__ ming_arr,
    float* __restrict__ out_labels, float* __restrict__ out_bboxes,
    float* __restrict__ out_fg,
    int* __restrict__ ws_tgt, float* __restrict__ ws_amv,
    int* __restrict__ pam, int* __restrict__ pim,
    int B, int G, int NA)
{
    __shared__ float4 sbox[64];
    __shared__ float smask[64];
    __shared__ int   slab[64];

    int b = blockIdx.y;
    int tid = threadIdx.x;
    if (tid < G) {
        sbox[tid]  = *(const float4*)(gt_bboxes + ((size_t)b * G + tid) * 4);
        smask[tid] = mask_gt[b * G + tid];
        slab[tid]  = gt_labels[b * G + tid];
    }
    __syncthreads();

    int a = blockIdx.x * blockDim.x + tid;
    if (a >= NA) return;
    size_t o = (size_t)b * NA + a;

    int cntv = cnt_arr[o];
    float4 p = *(const float4*)(pd_bboxes + o * 4);

    int tgt; float fgm;
    if (cntv > 1) {
        // disputed (rare): argmax IoU over ALL g (incl. invalid), first-occurrence
        float bi = -1.f; int bg = 0;
        #pragma unroll 4
        for (int g = 0; g < G; ++g) {
            float iou = iou_clip(sbox[g], p);
            if (iou > bi) { bi = iou; bg = g; }
        }
        tgt = bg; fgm = 1.f;
    } else {
        tgt = (cntv == 1) ? ming_arr[o] : 0;
        fgm = (float)cntv;
    }

    // recompute am/iou at target (bit-identical path to k_gt for cnt==1 case)
    float4 gbt = sbox[tgt];
    float ax = anc[2 * a], ay = anc[2 * a + 1];
    float sqs = sqrtf(fmaxf(pd_scores[o], 0.f));
    float vt = in_box(ax, ay, gbt) * smask[tgt];
    float iout = iou_clip(gbt, p);
    float amt = align_metric_f(sqs, iout, vt);
    float amv = (fgm != 0.f) ? amt : 0.f;   // am * mask_pos (includes valid)
    float iov = (fgm != 0.f) ? iout : 0.f;  // overlaps * mask_pos (NO valid mult)

    int lbl = slab[tgt]; if (lbl < 0) lbl = 0;
    out_labels[o] = (float)lbl;
    *(float4*)(out_bboxes + o * 4) = gbt;
    out_fg[o] = fgm;
    ws_tgt[o] = tgt;
    ws_amv[o] = amv;

    if (fgm != 0.f) {
        int gi = b * G + tgt;
        atomicMax(&pam[gi], __float_as_int(amv));  // values >= 0: int bits order == float order
        atomicMax(&pim[gi], __float_as_int(iov));
    }
}

// ---- Kernel 3: normalized target scores. ----
__global__ __launch_bounds__(256) void k_scores(
    const int* __restrict__ ws_tgt, const float* __restrict__ ws_amv,
    const int* __restrict__ pam, const int* __restrict__ pim,
    const float* __restrict__ out_labels,
    float* __restrict__ out_scores,
    int B, int G, int NA)
{
    int i = blockIdx.x * blockDim.x + threadIdx.x;
    if (i >= B * NA) return;
    int b = i / NA;
    int tgt = ws_tgt[i];
    float amv = ws_amv[i];
    float pa = __int_as_float(pam[b * G + tgt]);
    float pi = __int_as_float(pim[b * G + tgt]);
    float wgt = amv / (pa + 1e-9f) * pi;
    float onehot = (out_labels[i] == 0.f) ? 1.f : 0.f;  // NC==1
    out_scores[i] = onehot * wgt;
}

extern "C" void kernel_launch(void* const* d_in, const int* in_sizes, int n_in,
                              void* d_out, int out_size, void* d_ws, size_t ws_size,
                              hipStream_t stream) {
    const float* pd_scores = (const float*)d_in[0];
    const float* pd_bboxes = (const float*)d_in[1];
    const float* anc       = (const float*)d_in[2];
    const int*   gt_labels = (const int*)d_in[3];
    const float* gt_bboxes = (const float*)d_in[4];
    const float* mask_gt   = (const float*)d_in[5];

    int NA = in_sizes[2] / 2;
    int B  = in_sizes[0] / NA;
    int G  = in_sizes[4] / (B * 4);

    float* out = (float*)d_out;
    float* out_labels = out;                               // (B,NA)
    float* out_bboxes = out_labels + (size_t)B * NA;       // (B,NA,4)
    float* out_scores = out_bboxes + (size_t)B * NA * 4;   // (B,NA,1)
    float* out_fg     = out_scores + (size_t)B * NA;       // (B,NA)

    int BG = B * G;
    int BNA = B * NA;
    int* cnt    = (int*)d_ws;                   // BNA
    int* ming   = cnt + BNA;                    // BNA
    int* pam    = ming + BNA;                   // BG
    int* pim    = pam + BG;                     // BG
    int* ws_tgt = pim + BG;                     // BNA
    float* ws_amv = (float*)(ws_tgt + BNA);     // BNA

    k_init<<<dim3((BNA + 255) / 256), dim3(256), 0, stream>>>(cnt, ming, pam, pim, BNA, BG);

    k_gt<<<dim3((BG + 3) / 4), dim3(256), 0, stream>>>(
        pd_scores, pd_bboxes, gt_bboxes, mask_gt, cnt, ming, B, G, NA);

    k_anchor<<<dim3((NA + 255) / 256, B), dim3(256), 0, stream>>>(
        pd_scores, pd_bboxes, anc, gt_labels, gt_bboxes, mask_gt, cnt, ming,
        out_labels, out_bboxes, out_fg, ws_tgt, ws_amv, pam, pim, B, G, NA);

    k_scores<<<dim3((BNA + 255) / 256), dim3(256), 0, stream>>>(
        ws_tgt, ws_amv, pam, pim, out_labels, out_scores, B, G, NA);
}